// Round 14
// baseline (279.523 us; speedup 1.0000x reference)
//
#include <hip/hip_runtime.h>
#include <cstddef>

#define NB 4
#define NP 8192
#define NK 16
#define NC 128
#define HW_ 136   // center_k LDS stride (shorts)
#define GIW 136   // edge_k H stride (shorts)
#define AGW 136   // edge_k AGG stride (shorts)
#define CW  132   // edge_k C-table stride (floats)
#define UINW 264  // upd_k [agg|self] stride (shorts)
#define HUW 136

using short8   = __attribute__((ext_vector_type(8))) short;
using ushort4v = __attribute__((ext_vector_type(4))) unsigned short;
using floatx4  = __attribute__((ext_vector_type(4))) float;

union U8 { short8 s8; unsigned u[4]; };

__device__ __forceinline__ unsigned short f2bf(float f) {
    union { float f; unsigned u; } v; v.f = f;
    unsigned r = v.u + 0x7FFFu + ((v.u >> 16) & 1u);   // RNE
    return (unsigned short)(r >> 16);
}
__device__ __forceinline__ float bf2f(unsigned short u) {
    union { unsigned u; float f; } v; v.u = ((unsigned)u) << 16;
    return v.f;
}
__device__ __forceinline__ unsigned cvt_pk_bf16(float lo, float hi) {
    unsigned d;
    asm("v_cvt_pk_bf16_f32 %0, %1, %2" : "=v"(d) : "v"(lo), "v"(hi));
    return d;
}

#define MFMA(a, b, c) __builtin_amdgcn_mfma_f32_16x16x32_bf16((a), (b), (c), 0, 0, 0)

// H-fragment transform: relu(G~ - C), packed to bf16
__device__ __forceinline__ short8 xform(short8 g, floatx4 ca, floatx4 cb) {
    U8 u;
    u.u[0] = cvt_pk_bf16(fmaxf(bf2f((unsigned short)g[0]) - ca[0], 0.f),
                         fmaxf(bf2f((unsigned short)g[1]) - ca[1], 0.f));
    u.u[1] = cvt_pk_bf16(fmaxf(bf2f((unsigned short)g[2]) - ca[2], 0.f),
                         fmaxf(bf2f((unsigned short)g[3]) - ca[3], 0.f));
    u.u[2] = cvt_pk_bf16(fmaxf(bf2f((unsigned short)g[4]) - cb[0], 0.f),
                         fmaxf(bf2f((unsigned short)g[5]) - cb[1], 0.f));
    u.u[3] = cvt_pk_bf16(fmaxf(bf2f((unsigned short)g[6]) - cb[2], 0.f),
                         fmaxf(bf2f((unsigned short)g[7]) - cb[3], 0.f));
    return u.s8;
}

// ---------------------------------------------------------------------------
// Weight packing (round-13 version, verified).
// ---------------------------------------------------------------------------
__global__ void pack_weights_k(const float* __restrict__ offW1,
                               const float* __restrict__ eW1,
                               const float* __restrict__ eW2,
                               const float* __restrict__ uW1,
                               const float* __restrict__ uW2,
                               const float* __restrict__ eb1,
                               unsigned short* __restrict__ offW1p,
                               unsigned short* __restrict__ eW1fp,
                               unsigned short* __restrict__ eW2p,
                               unsigned short* __restrict__ uW1p,
                               unsigned short* __restrict__ uW2p,
                               float* __restrict__ eW1rTp)
{
    int i = blockIdx.x * 256 + threadIdx.x;
    if (i < 16384) { offW1p[i] = f2bf(offW1[i]); return; }
    i -= 16384;
    if (i < 49152) {
        int tt = i / 16384, rem = i % 16384;
        int o = rem / 128, k = rem % 128;
        eW1fp[i] = f2bf(eW1[(tt * 128 + o) * 131 + 3 + k]);
        return;
    }
    i -= 49152;
    if (i < 49152) { eW2p[i] = f2bf(eW2[i]); return; }
    i -= 49152;
    if (i < 98304) { uW1p[i] = f2bf(uW1[i]); return; }
    i -= 98304;
    if (i < 49152) { uW2p[i] = f2bf(uW2[i]); return; }
    i -= 49152;
    if (i < 1536) {
        int tt = i / 512, rem = i % 512;
        int j = rem / 128, col = rem % 128;
        eW1rTp[i] = (j < 3) ? eW1[(size_t)(tt * 128 + col) * 131 + j]
                            : eb1[tt * 128 + col];
    }
}

// ---------------------------------------------------------------------------
// center_k: round-13 version (verified).
// ---------------------------------------------------------------------------
__global__ __launch_bounds__(256, 4)
void center_k(const float* __restrict__ Fin, const float* __restrict__ xyz,
              const unsigned short* __restrict__ offW1p,
              const float* __restrict__ offW2, const float* __restrict__ offb1,
              const float* __restrict__ offb2,
              const unsigned short* __restrict__ eW1fp,
              const float* __restrict__ eW1rT0,   // packed [4][128] (t=0)
              unsigned short* __restrict__ Gbf, float* __restrict__ ctr)
{
    __shared__ __align__(16) unsigned short sA[32 * HW_];
    __shared__ __align__(16) unsigned short sH[32 * HW_];
    __shared__ float s_XY[96];
    const int t = threadIdx.x, wv = t >> 6, ln = t & 63, q = ln >> 4, r = ln & 15;
    const int cg0 = wv << 1;
    const int base = blockIdx.x * 32;

    {   // 32x128 fp32 -> bf16 -> sA
        int row = t >> 3, c16 = (t & 7) * 16;
        const float* src = Fin + (size_t)(base + row) * NC + c16;
        float4 f0 = *(const float4*)src;
        float4 f1 = *(const float4*)(src + 4);
        float4 f2 = *(const float4*)(src + 8);
        float4 f3 = *(const float4*)(src + 12);
        short8 u0, u1;
        u0[0]=f2bf(f0.x); u0[1]=f2bf(f0.y); u0[2]=f2bf(f0.z); u0[3]=f2bf(f0.w);
        u0[4]=f2bf(f1.x); u0[5]=f2bf(f1.y); u0[6]=f2bf(f1.z); u0[7]=f2bf(f1.w);
        u1[0]=f2bf(f2.x); u1[1]=f2bf(f2.y); u1[2]=f2bf(f2.z); u1[3]=f2bf(f2.w);
        u1[4]=f2bf(f3.x); u1[5]=f2bf(f3.y); u1[6]=f2bf(f3.z); u1[7]=f2bf(f3.w);
        *(short8*)&sA[row * HW_ + c16]     = u0;
        *(short8*)&sA[row * HW_ + c16 + 8] = u1;
    }
    if (t < 96) s_XY[t] = xyz[(size_t)base * 3 + t];
    __syncthreads();

    floatx4 agk[2][2];
    {   // offset L1 + G-GEMM
        short8 wo[2][4], wg[2][4];
#pragma unroll
        for (int c = 0; c < 2; ++c)
#pragma unroll
            for (int ks = 0; ks < 4; ++ks) {
                wo[c][ks] = *(const short8*)(offW1p + ((cg0 + c) * 16 + r) * NC + ks * 32 + q * 8);
                wg[c][ks] = *(const short8*)(eW1fp  + ((cg0 + c) * 16 + r) * NC + ks * 32 + q * 8);
            }
        float bo[2] = { offb1[cg0 * 16 + r], offb1[(cg0 + 1) * 16 + r] };
#pragma unroll
        for (int rt = 0; rt < 2; ++rt) {
            short8 af[4];
#pragma unroll
            for (int ks = 0; ks < 4; ++ks)
                af[ks] = *(const short8*)&sA[(rt * 16 + r) * HW_ + ks * 32 + q * 8];
            floatx4 ao[2] = { {0.f,0.f,0.f,0.f}, {0.f,0.f,0.f,0.f} };
            floatx4 ag[2] = { {0.f,0.f,0.f,0.f}, {0.f,0.f,0.f,0.f} };
#pragma unroll
            for (int c = 0; c < 2; ++c)
#pragma unroll
                for (int ks = 0; ks < 4; ++ks) {
                    ao[c] = MFMA(af[ks], wo[c][ks], ao[c]);
                    ag[c] = MFMA(af[ks], wg[c][ks], ag[c]);
                }
#pragma unroll
            for (int c = 0; c < 2; ++c) {
                int col = (cg0 + c) * 16 + r;
#pragma unroll
                for (int i = 0; i < 4; ++i)
                    sH[(rt * 16 + q * 4 + i) * HW_ + col] = f2bf(fmaxf(ao[c][i] + bo[c], 0.f));
                agk[rt][c] = ag[c];
            }
        }
    }
    __syncthreads();

    {   // stage G~ -> sA with xyz*W1r + b1 fold (packed, coalesced)
#pragma unroll
        for (int c = 0; c < 2; ++c) {
            int col = (cg0 + c) * 16 + r;
            float w0 = eW1rT0[col], w1 = eW1rT0[128 + col];
            float w2 = eW1rT0[256 + col], b1v = eW1rT0[384 + col];
#pragma unroll
            for (int rt = 0; rt < 2; ++rt)
#pragma unroll
                for (int i = 0; i < 4; ++i) {
                    int row = rt * 16 + q * 4 + i;
                    sA[row * HW_ + col] = f2bf(agk[rt][c][i]
                        + s_XY[row * 3 + 0] * w0 + s_XY[row * 3 + 1] * w1
                        + s_XY[row * 3 + 2] * w2 + b1v);
                }
        }
    }
    if (wv < 2) {   // offset L2 (out=3)
        int rt = wv;
        short8 wf[4];
#pragma unroll
        for (int ks = 0; ks < 4; ++ks) {
            short8 u = {0,0,0,0,0,0,0,0};
            if (r < 3) {
                const float* w = offW2 + r * NC + ks * 32 + q * 8;
                float4 f0 = *(const float4*)w;
                float4 f1 = *(const float4*)(w + 4);
                u[0]=f2bf(f0.x); u[1]=f2bf(f0.y); u[2]=f2bf(f0.z); u[3]=f2bf(f0.w);
                u[4]=f2bf(f1.x); u[5]=f2bf(f1.y); u[6]=f2bf(f1.z); u[7]=f2bf(f1.w);
            }
            wf[ks] = u;
        }
        short8 af[4];
#pragma unroll
        for (int ks = 0; ks < 4; ++ks)
            af[ks] = *(const short8*)&sH[(rt * 16 + r) * HW_ + ks * 32 + q * 8];
        floatx4 acc = {0.f, 0.f, 0.f, 0.f};
#pragma unroll
        for (int ks = 0; ks < 4; ++ks)
            acc = MFMA(af[ks], wf[ks], acc);
        if (r < 3) {
#pragma unroll
            for (int i = 0; i < 4; ++i) {
                int p = rt * 16 + q * 4 + i;
                ctr[(size_t)(base + p) * 3 + r] =
                    xyz[(size_t)(base + p) * 3 + r] + acc[i] + offb2[r];
            }
        }
    }
    __syncthreads();

    {   // coalesced Gbf write
        int row = t >> 3, c16 = (t & 7) * 16;
        *(short8*)(Gbf + (size_t)(base + row) * NC + c16)     = *(short8*)&sA[row * HW_ + c16];
        *(short8*)(Gbf + (size_t)(base + row) * NC + c16 + 8) = *(short8*)&sA[row * HW_ + c16 + 8];
    }
}

// ---------------------------------------------------------------------------
// edge_k v7: 2-tile grid-stride (grid 2048). Each block runs the verified
// v6 phase machinery over TWO 8-point tiles: P0 (knn + wf2 + C-table for
// all 16 points + tile-0 gathers) paid once; tile-1 gathers issued in two
// 16-reg batches DURING tile-0's MFMA phases (latency hidden). Barriers
// 9/2-tiles vs 10; weight loads halved. LDS 28032 B.
// ---------------------------------------------------------------------------
__global__ __launch_bounds__(256, 2)
void edge_k(const unsigned short* __restrict__ Gbf,
            const int* __restrict__ knn,
            const float* __restrict__ ctr,
            const float* __restrict__ eW1rT,   // packed [4][128] + t*512
            const float* __restrict__ eb2,
            const unsigned short* __restrict__ eW2p,
            unsigned short* __restrict__ aggG)
{
    __shared__ __align__(16) unsigned short s_H[64 * GIW];    // 17408 B
    __shared__ __align__(16) float s_C[16 * CW];              // 8448 B
    __shared__ __align__(16) unsigned short s_AGB[8 * AGW];   // 2176 B

    // XCD swizzle: batch b -> XCDs {2b, 2b+1}
    const int xcd  = blockIdx.x & 7;
    const int slot = blockIdx.x >> 3;          // 0..255
    const int b    = xcd >> 1;
    const int base0 = b * NP + ((((slot << 1) | 0) << 1 | (xcd & 1)) << 3);
    const int base1 = b * NP + ((((slot << 1) | 1) << 1 | (xcd & 1)) << 3);
    const int t = threadIdx.x, wv = t >> 6, ln = t & 63;
    const int q = ln >> 4, r = ln & 15, cg0 = wv << 1;
    const int rr = t >> 4, c8 = (t & 15) * 8;

    // ---- P0: knn both tiles, tile-0 gathers (both halves), W2, C-table x16
    const int* kb0 = knn + (size_t)base0 * NK;
    const int* kb1 = knn + (size_t)base1 * NK;
    int kn0[8], kn1[8];
#pragma unroll
    for (int j = 0; j < 8; ++j) { kn0[j] = kb0[j * 16 + rr]; kn1[j] = kb1[j * 16 + rr]; }
    short8 gA[8];
#pragma unroll
    for (int p = 0; p < 8; ++p)
        gA[p] = *(const short8*)(Gbf + (size_t)(b * NP + kn0[p]) * NC + c8);

    short8 wf2[2][4];
#pragma unroll
    for (int c = 0; c < 2; ++c)
#pragma unroll
        for (int ks = 0; ks < 4; ++ks)
            wf2[c][ks] = *(const short8*)(eW2p + ((cg0 + c) * 16 + r) * NC + ks * 32 + q * 8);
    float eb2v[2] = { eb2[cg0 * 16 + r], eb2[(cg0 + 1) * 16 + r] };

    {   // C[p16][col] = ctr . W1r — 16 points (8 per tile), packed coalesced
        int p16 = t >> 4, c0 = (t & 15) * 8;
        int pb = (p16 < 8) ? (base0 + p16) : (base1 + (p16 - 8));
        float cx = ctr[(size_t)pb * 3 + 0];
        float cy = ctr[(size_t)pb * 3 + 1];
        float cz = ctr[(size_t)pb * 3 + 2];
        floatx4 w0a = *(const floatx4*)(eW1rT + c0);
        floatx4 w0b = *(const floatx4*)(eW1rT + c0 + 4);
        floatx4 w1a = *(const floatx4*)(eW1rT + 128 + c0);
        floatx4 w1b = *(const floatx4*)(eW1rT + 128 + c0 + 4);
        floatx4 w2a = *(const floatx4*)(eW1rT + 256 + c0);
        floatx4 w2b = *(const floatx4*)(eW1rT + 256 + c0 + 4);
#pragma unroll
        for (int k = 0; k < 4; ++k) {
            s_C[p16 * CW + c0 + k]     = cx * w0a[k] + cy * w1a[k] + cz * w2a[k];
            s_C[p16 * CW + c0 + 4 + k] = cx * w0b[k] + cy * w1b[k] + cz * w2b[k];
        }
    }
    __syncthreads();   // ==== A: C ready ====

    // ---- xform t0h0 -> s_H
#pragma unroll
    for (int p = 0; p < 4; ++p) {
        const float* cp = &s_C[p * CW + c8];
        *(short8*)&s_H[(p * 16 + rr) * GIW + c8] =
            xform(gA[p], *(const floatx4*)cp, *(const floatx4*)(cp + 4));
    }
    __syncthreads();   // ==== B ====

    // ---- issue tile-1 half-0 gathers; MFMA t0h0 -> AGB rows 0..3
    short8 gB0[4];
#pragma unroll
    for (int p = 0; p < 4; ++p)
        gB0[p] = *(const short8*)(Gbf + (size_t)(b * NP + kn1[p]) * NC + c8);
#pragma unroll
    for (int rt = 0; rt < 4; ++rt) {
        short8 af[4];
#pragma unroll
        for (int ks = 0; ks < 4; ++ks)
            af[ks] = *(const short8*)&s_H[(rt * 16 + r) * GIW + ks * 32 + q * 8];
        floatx4 acc[2] = { {0.f,0.f,0.f,0.f}, {0.f,0.f,0.f,0.f} };
#pragma unroll
        for (int c = 0; c < 2; ++c)
#pragma unroll
            for (int ks = 0; ks < 4; ++ks)
                acc[c] = MFMA(af[ks], wf2[c][ks], acc[c]);
#pragma unroll
        for (int c = 0; c < 2; ++c) {
            float m = fmaxf(fmaxf(acc[c][0], acc[c][1]), fmaxf(acc[c][2], acc[c][3]));
            m = fmaxf(m, __shfl_xor(m, 16));
            m = fmaxf(m, __shfl_xor(m, 32));
            if (q == 0)
                s_AGB[rt * AGW + (cg0 + c) * 16 + r] = f2bf(m + eb2v[c]);
        }
    }
    __syncthreads();   // ==== C ====

    // ---- xform t0h1 -> s_H
#pragma unroll
    for (int p = 0; p < 4; ++p) {
        const float* cp = &s_C[(4 + p) * CW + c8];
        *(short8*)&s_H[(p * 16 + rr) * GIW + c8] =
            xform(gA[4 + p], *(const floatx4*)cp, *(const floatx4*)(cp + 4));
    }
    __syncthreads();   // ==== D ====

    // ---- issue tile-1 half-1 gathers; MFMA t0h1 -> AGB rows 4..7
    short8 gB1[4];
#pragma unroll
    for (int p = 0; p < 4; ++p)
        gB1[p] = *(const short8*)(Gbf + (size_t)(b * NP + kn1[4 + p]) * NC + c8);
#pragma unroll
    for (int rt = 0; rt < 4; ++rt) {
        short8 af[4];
#pragma unroll
        for (int ks = 0; ks < 4; ++ks)
            af[ks] = *(const short8*)&s_H[(rt * 16 + r) * GIW + ks * 32 + q * 8];
        floatx4 acc[2] = { {0.f,0.f,0.f,0.f}, {0.f,0.f,0.f,0.f} };
#pragma unroll
        for (int c = 0; c < 2; ++c)
#pragma unroll
            for (int ks = 0; ks < 4; ++ks)
                acc[c] = MFMA(af[ks], wf2[c][ks], acc[c]);
#pragma unroll
        for (int c = 0; c < 2; ++c) {
            float m = fmaxf(fmaxf(acc[c][0], acc[c][1]), fmaxf(acc[c][2], acc[c][3]));
            m = fmaxf(m, __shfl_xor(m, 16));
            m = fmaxf(m, __shfl_xor(m, 32));
            if (q == 0)
                s_AGB[(4 + rt) * AGW + (cg0 + c) * 16 + r] = f2bf(m + eb2v[c]);
        }
    }
    __syncthreads();   // ==== E: tile-0 AGG ready ====

    // ---- dump tile-0 AGG; xform t1h0 -> s_H (s_H free after barrier E)
    if (t < 128) {
        int row = t >> 4, cc = (t & 15) * 8;
        *(short8*)(aggG + (size_t)(base0 + row) * NC + cc) = *(short8*)&s_AGB[row * AGW + cc];
    }
#pragma unroll
    for (int p = 0; p < 4; ++p) {
        const float* cp = &s_C[(8 + p) * CW + c8];
        *(short8*)&s_H[(p * 16 + rr) * GIW + c8] =
            xform(gB0[p], *(const floatx4*)cp, *(const floatx4*)(cp + 4));
    }
    __syncthreads();   // ==== F ====

    // ---- MFMA t1h0 -> AGB rows 0..3 (tile-0 dump complete)
#pragma unroll
    for (int rt = 0; rt < 4; ++rt) {
        short8 af[4];
#pragma unroll
        for (int ks = 0; ks < 4; ++ks)
            af[ks] = *(const short8*)&s_H[(rt * 16 + r) * GIW + ks * 32 + q * 8];
        floatx4 acc[2] = { {0.f,0.f,0.f,0.f}, {0.f,0.f,0.f,0.f} };
#pragma unroll
        for (int c = 0; c < 2; ++c)
#pragma unroll
            for (int ks = 0; ks < 4; ++ks)
                acc[c] = MFMA(af[ks], wf2[c][ks], acc[c]);
#pragma unroll
        for (int c = 0; c < 2; ++c) {
            float m = fmaxf(fmaxf(acc[c][0], acc[c][1]), fmaxf(acc[c][2], acc[c][3]));
            m = fmaxf(m, __shfl_xor(m, 16));
            m = fmaxf(m, __shfl_xor(m, 32));
            if (q == 0)
                s_AGB[rt * AGW + (cg0 + c) * 16 + r] = f2bf(m + eb2v[c]);
        }
    }
    __syncthreads();   // ==== G ====

    // ---- xform t1h1 -> s_H
#pragma unroll
    for (int p = 0; p < 4; ++p) {
        const float* cp = &s_C[(12 + p) * CW + c8];
        *(short8*)&s_H[(p * 16 + rr) * GIW + c8] =
            xform(gB1[p], *(const floatx4*)cp, *(const floatx4*)(cp + 4));
    }
    __syncthreads();   // ==== H ====

    // ---- MFMA t1h1 -> AGB rows 4..7
#pragma unroll
    for (int rt = 0; rt < 4; ++rt) {
        short8 af[4];
#pragma unroll
        for (int ks = 0; ks < 4; ++ks)
            af[ks] = *(const short8*)&s_H[(rt * 16 + r) * GIW + ks * 32 + q * 8];
        floatx4 acc[2] = { {0.f,0.f,0.f,0.f}, {0.f,0.f,0.f,0.f} };
#pragma unroll
        for (int c = 0; c < 2; ++c)
#pragma unroll
            for (int ks = 0; ks < 4; ++ks)
                acc[c] = MFMA(af[ks], wf2[c][ks], acc[c]);
#pragma unroll
        for (int c = 0; c < 2; ++c) {
            float m = fmaxf(fmaxf(acc[c][0], acc[c][1]), fmaxf(acc[c][2], acc[c][3]));
            m = fmaxf(m, __shfl_xor(m, 16));
            m = fmaxf(m, __shfl_xor(m, 32));
            if (q == 0)
                s_AGB[(4 + rt) * AGW + (cg0 + c) * 16 + r] = f2bf(m + eb2v[c]);
        }
    }
    __syncthreads();   // ==== I: tile-1 AGG ready ====

    if (t < 128) {
        int row = t >> 4, cc = (t & 15) * 8;
        *(short8*)(aggG + (size_t)(base1 + row) * NC + cc) = *(short8*)&s_AGB[row * AGW + cc];
    }
}

// ---------------------------------------------------------------------------
// upd_k: round-13 version (verified).
// ---------------------------------------------------------------------------
__global__ __launch_bounds__(256, 3)
void upd_k(const float* __restrict__ Fin, float* __restrict__ Fout,
           const unsigned short* __restrict__ aggG,
           const float* __restrict__ xyz,
           const unsigned short* __restrict__ uW1p,
           const unsigned short* __restrict__ uW2p,
           const float* __restrict__ ub1, const float* __restrict__ ub2,
           const unsigned short* __restrict__ eW1fpN,   // next iter G-proj (bf16)
           const float* __restrict__ eW1rTN,            // next iter packed [4][128]
           const unsigned short* __restrict__ offW1p,
           const float* __restrict__ offW2, const float* __restrict__ offb1,
           const float* __restrict__ offb2,
           unsigned short* __restrict__ Gbf, float* __restrict__ ctrOut,
           int doNext)
{
    __shared__ __align__(16) unsigned short s_UIN[32 * UINW];  // 16896 B
    __shared__ __align__(16) unsigned short s_H[32 * HUW];     // 8704 B
    __shared__ __align__(16) unsigned short s_FN[32 * HUW];    // 8704 B
    __shared__ float s_XY[96];

    const int xcd  = blockIdx.x & 7;
    const int slot = blockIdx.x >> 3;
    const int b    = xcd >> 1;
    const int n0   = ((slot << 1) | (xcd & 1)) << 5;   // *32
    const int t = threadIdx.x, wv = t >> 6, ln = t & 63;
    const int q = ln >> 4, r = ln & 15, cg0 = wv << 1;
    const int base = b * NP + n0;
    const int row32 = t >> 3, c16 = (t & 7) * 16;

    // ---- P0: stage UIN = [agg(bf16) | self(f32->bf16)] for 32 rows; xyz
    {
        const unsigned short* ap = aggG + (size_t)(base + row32) * NC + c16;
        *(short8*)&s_UIN[row32 * UINW + c16]     = *(const short8*)ap;
        *(short8*)&s_UIN[row32 * UINW + c16 + 8] = *(const short8*)(ap + 8);
        const float* src = Fin + (size_t)(base + row32) * NC + c16;
        float4 f0 = *(const float4*)src;
        float4 f1 = *(const float4*)(src + 4);
        float4 f2 = *(const float4*)(src + 8);
        float4 f3 = *(const float4*)(src + 12);
        short8 u0, u1;
        u0[0]=f2bf(f0.x); u0[1]=f2bf(f0.y); u0[2]=f2bf(f0.z); u0[3]=f2bf(f0.w);
        u0[4]=f2bf(f1.x); u0[5]=f2bf(f1.y); u0[6]=f2bf(f1.z); u0[7]=f2bf(f1.w);
        u1[0]=f2bf(f2.x); u1[1]=f2bf(f2.y); u1[2]=f2bf(f2.z); u1[3]=f2bf(f2.w);
        u1[4]=f2bf(f3.x); u1[5]=f2bf(f3.y); u1[6]=f2bf(f3.z); u1[7]=f2bf(f3.w);
        *(short8*)&s_UIN[row32 * UINW + 128 + c16]     = u0;
        *(short8*)&s_UIN[row32 * UINW + 128 + c16 + 8] = u1;
    }
    if (t < 96) s_XY[t] = xyz[(size_t)base * 3 + t];
    __syncthreads();   // ==== A ====

    // ---- upd-L1 (K=256) -> H, 2 row-tiles per weight load
    {
        short8 wfa[2][8];
#pragma unroll
        for (int c = 0; c < 2; ++c)
#pragma unroll
            for (int ks = 0; ks < 8; ++ks)
                wfa[c][ks] = *(const short8*)(uW1p + ((cg0 + c) * 16 + r) * 256 + ks * 32 + q * 8);
        float ub1v[2] = { ub1[cg0 * 16 + r], ub1[(cg0 + 1) * 16 + r] };
#pragma unroll
        for (int rt = 0; rt < 2; ++rt) {
            short8 af[8];
#pragma unroll
            for (int ks = 0; ks < 8; ++ks)
                af[ks] = *(const short8*)&s_UIN[(rt * 16 + r) * UINW + ks * 32 + q * 8];
            floatx4 acc3[2] = { {0.f,0.f,0.f,0.f}, {0.f,0.f,0.f,0.f} };
#pragma unroll
            for (int c = 0; c < 2; ++c)
#pragma unroll
                for (int ks = 0; ks < 8; ++ks)
                    acc3[c] = MFMA(af[ks], wfa[c][ks], acc3[c]);
#pragma unroll
            for (int c = 0; c < 2; ++c)
#pragma unroll
                for (int i = 0; i < 4; ++i)
                    s_H[(rt * 16 + q * 4 + i) * HUW + (cg0 + c) * 16 + r] =
                        f2bf(fmaxf(acc3[c][i] + ub1v[c], 0.f));
        }
    }
    __syncthreads();   // ==== B ====

    // ---- upd-L2 + residual -> Fout; Fnew bf16 -> s_FN
    {
        short8 wfb[2][4];
#pragma unroll
        for (int c = 0; c < 2; ++c)
#pragma unroll
            for (int ks = 0; ks < 4; ++ks)
                wfb[c][ks] = *(const short8*)(uW2p + ((cg0 + c) * 16 + r) * NC + ks * 32 + q * 8);
        float ub2v[2] = { ub2[cg0 * 16 + r], ub2[(cg0 + 1) * 16 + r] };
#pragma unroll
        for (int rt = 0; rt < 2; ++rt) {
            short8 af[4];
#pragma unroll
            for (int ks = 0; ks < 4; ++ks)
                af[ks] = *(const short8*)&s_H[(rt * 16 + r) * HUW + ks * 32 + q * 8];
            floatx4 acc[2] = { {0.f,0.f,0.f,0.f}, {0.f,0.f,0.f,0.f} };
#pragma unroll
            for (int c = 0; c < 2; ++c)
#pragma unroll
                for (int ks = 0; ks < 4; ++ks)
                    acc[c] = MFMA(af[ks], wfb[c][ks], acc[c]);
#pragma unroll
            for (int c = 0; c < 2; ++c) {
                int col = (cg0 + c) * 16 + r;
#pragma unroll
                for (int i = 0; i < 4; ++i) {
                    int p = rt * 16 + q * 4 + i;   // 0..31
                    float fnew = Fin[(size_t)(base + p) * NC + col] + acc[c][i] + ub2v[c];
                    Fout[(size_t)(base + p) * NC + col] = fnew;
                    s_FN[p * HUW + col] = f2bf(fnew);
                }
            }
        }
    }

    if (doNext) {
        __syncthreads();   // ==== C ====
        // ---- G~' = Fnew*W1f^T + xyz*W1rN + b1N -> s_UIN; off-L1 -> s_H
        {
            short8 wg[2][4], wo[2][4];
#pragma unroll
            for (int c = 0; c < 2; ++c)
#pragma unroll
                for (int ks = 0; ks < 4; ++ks) {
                    wg[c][ks] = *(const short8*)(eW1fpN + ((cg0 + c) * 16 + r) * NC + ks * 32 + q * 8);
                    wo[c][ks] = *(const short8*)(offW1p + ((cg0 + c) * 16 + r) * NC + ks * 32 + q * 8);
                }
            float bo[2] = { offb1[cg0 * 16 + r], offb1[(cg0 + 1) * 16 + r] };
#pragma unroll
            for (int rt = 0; rt < 2; ++rt) {
                short8 af[4];
#pragma unroll
                for (int ks = 0; ks < 4; ++ks)
                    af[ks] = *(const short8*)&s_FN[(rt * 16 + r) * HUW + ks * 32 + q * 8];
                floatx4 ag[2] = { {0.f,0.f,0.f,0.f}, {0.f,0.f,0.f,0.f} };
                floatx4 ao[2] = { {0.f,0.f,0.f,0.f}, {0.f,0.f,0.f,0.f} };
#pragma unroll
                for (int c = 0; c < 2; ++c)
#pragma unroll
                    for (int ks = 0; ks < 4; ++ks) {
                        ag[c] = MFMA(af[ks], wg[c][ks], ag[c]);
                        ao[c] = MFMA(af[ks], wo[c][ks], ao[c]);
                    }
#pragma unroll
                for (int c = 0; c < 2; ++c) {
                    int col = (cg0 + c) * 16 + r;
                    float w0 = eW1rTN[col], w1 = eW1rTN[128 + col];
                    float w2 = eW1rTN[256 + col], b1v = eW1rTN[384 + col];
#pragma unroll
                    for (int i = 0; i < 4; ++i) {
                        int p = rt * 16 + q * 4 + i;
                        s_UIN[p * UINW + col] = f2bf(ag[c][i]
                            + s_XY[p * 3 + 0] * w0 + s_XY[p * 3 + 1] * w1
                            + s_XY[p * 3 + 2] * w2 + b1v);
                        s_H[p * HUW + col]    = f2bf(fmaxf(ao[c][i] + bo[c], 0.f));
                    }
                }
            }
        }
        __syncthreads();   // ==== D ====

        // coalesced Gbf dump (32 rows)
        *(short8*)(Gbf + (size_t)(base + row32) * NC + c16) =
            *(short8*)&s_UIN[row32 * UINW + c16];
        *(short8*)(Gbf + (size_t)(base + row32) * NC + c16 + 8) =
            *(short8*)&s_UIN[row32 * UINW + c16 + 8];

        if (wv < 2) {   // off-L2 (out=3) -> ctr', one 16-row tile per wave
            int rt = wv;
            short8 wf[4];
#pragma unroll
            for (int ks = 0; ks < 4; ++ks) {
                short8 u = {0,0,0,0,0,0,0,0};
                if (r < 3) {
                    const float* w = offW2 + r * NC + ks * 32 + q * 8;
                    float4 f0 = *(const float4*)w;
                    float4 f1 = *(const float4*)(w + 4);
                    u[0]=f2bf(f0.x); u[1]=f2bf(f0.y); u[2]=f2bf(f0.z); u[3]=f2bf(f0.w);
                    u[4]=f2bf(f1.x); u[5]=f2bf(f1.y); u[6]=f2bf(f1.z); u[7]=f2bf(f1.w);
                }
                wf[ks] = u;
            }
            short8 af[4];
#pragma unroll
            for (int ks = 0; ks < 4; ++ks)
                af[ks] = *(const short8*)&s_H[(rt * 16 + r) * HUW + ks * 32 + q * 8];
            floatx4 acc = {0.f, 0.f, 0.f, 0.f};
#pragma unroll
            for (int ks = 0; ks < 4; ++ks)
                acc = MFMA(af[ks], wf[ks], acc);
            if (r < 3) {
#pragma unroll
                for (int i = 0; i < 4; ++i) {
                    int p = rt * 16 + q * 4 + i;
                    ctrOut[(size_t)(base + p) * 3 + r] =
                        xyz[(size_t)(base + p) * 3 + r] + acc[i] + offb2[r];
                }
            }
        }
    }
}

// ---------------------------------------------------------------------------
extern "C" void kernel_launch(void* const* d_in, const int* in_sizes, int n_in,
                              void* d_out, int out_size, void* d_ws, size_t ws_size,
                              hipStream_t stream)
{
    const float* xyz   = (const float*)d_in[0];
    const float* feat  = (const float*)d_in[1];
    const int*   knn   = (const int*)d_in[2];
    const float* offW1 = (const float*)d_in[3];
    const float* offb1 = (const float*)d_in[4];
    const float* offW2 = (const float*)d_in[5];
    const float* offb2 = (const float*)d_in[6];
    const float* eW1   = (const float*)d_in[7];
    const float* eb1   = (const float*)d_in[8];
    const float* eW2   = (const float*)d_in[9];
    const float* eb2   = (const float*)d_in[10];
    const float* uW1   = (const float*)d_in[11];
    const float* ub1   = (const float*)d_in[12];
    const float* uW2   = (const float*)d_in[13];
    const float* ub2   = (const float*)d_in[14];
    float* out = (float*)d_out;

    char* ws = (char*)d_ws;
    unsigned short* Gbf    = (unsigned short*)ws;                 // 8388608 B
    float*          ctrb   = (float*)(ws + 8388608);              // 393216 B
    unsigned short* offW1p = (unsigned short*)(ws + 8781824);     // 32768 B
    unsigned short* eW1fp  = (unsigned short*)(ws + 8814592);     // 98304 B
    unsigned short* eW2p   = (unsigned short*)(ws + 8912896);     // 98304 B
    unsigned short* uW1p   = (unsigned short*)(ws + 9011200);     // 196608 B
    unsigned short* uW2p   = (unsigned short*)(ws + 9207808);     // 98304 B
    unsigned short* aggG   = (unsigned short*)(ws + 9306112);     // 8388608 B
    float*          eW1rTp = (float*)(ws + 17694720);             // 6144 B

    pack_weights_k<<<1030, 256, 0, stream>>>(offW1, eW1, eW2, uW1, uW2, eb1,
                                             offW1p, eW1fp, eW2p, uW1p, uW2p,
                                             eW1rTp);

    // initial G~(0), ctr(0) from feat
    center_k<<<1024, 256, 0, stream>>>(feat, xyz, offW1p, offW2,
                                       offb1, offb2, eW1fp, eW1rTp,
                                       Gbf, ctrb);

    for (int tt = 0; tt < 3; ++tt) {
        int ntt = (tt + 1) % 3;
        edge_k<<<2048, 256, 0, stream>>>(
            Gbf, knn, ctrb,
            eW1rTp + tt * 512, eb2 + tt * 128,
            eW2p + tt * 16384, aggG);
        const float* fin = (tt == 0) ? feat : out;
        upd_k<<<1024, 256, 0, stream>>>(
            fin, out, aggG, xyz,
            uW1p + tt * 32768, uW2p + tt * 16384, ub1 + tt * 128, ub2 + tt * 128,
            eW1fp + ntt * 16384, eW1rTp + ntt * 512,
            offW1p, offW2, offb1, offb2,
            Gbf, ctrb, (tt < 2) ? 1 : 0);
    }
}

// Round 15
// 277.489 us; speedup vs baseline: 1.0073x; 1.0073x over previous
//
#include <hip/hip_runtime.h>
#include <cstddef>

#define NB 4
#define NP 8192
#define NK 16
#define NC 128
#define HW_ 136   // center_k LDS stride (shorts)
#define GIW 136   // edge_k H stride (shorts)
#define AGW 136   // edge_k AGG stride (shorts)
#define CW  132   // edge_k C-table stride (floats)
#define UINW 264  // upd_k [agg|self] stride (shorts)
#define HUW 136

using short8   = __attribute__((ext_vector_type(8))) short;
using ushort4v = __attribute__((ext_vector_type(4))) unsigned short;
using floatx4  = __attribute__((ext_vector_type(4))) float;

union U8 { short8 s8; unsigned u[4]; };

__device__ __forceinline__ unsigned short f2bf(float f) {
    union { float f; unsigned u; } v; v.f = f;
    unsigned r = v.u + 0x7FFFu + ((v.u >> 16) & 1u);   // RNE
    return (unsigned short)(r >> 16);
}
__device__ __forceinline__ float bf2f(unsigned short u) {
    union { unsigned u; float f; } v; v.u = ((unsigned)u) << 16;
    return v.f;
}
__device__ __forceinline__ unsigned cvt_pk_bf16(float lo, float hi) {
    unsigned d;
    asm("v_cvt_pk_bf16_f32 %0, %1, %2" : "=v"(d) : "v"(lo), "v"(hi));
    return d;
}

#define MFMA(a, b, c) __builtin_amdgcn_mfma_f32_16x16x32_bf16((a), (b), (c), 0, 0, 0)

// H-fragment transform: relu(G~ - C), packed to bf16
__device__ __forceinline__ short8 xform(short8 g, floatx4 ca, floatx4 cb) {
    U8 u;
    u.u[0] = cvt_pk_bf16(fmaxf(bf2f((unsigned short)g[0]) - ca[0], 0.f),
                         fmaxf(bf2f((unsigned short)g[1]) - ca[1], 0.f));
    u.u[1] = cvt_pk_bf16(fmaxf(bf2f((unsigned short)g[2]) - ca[2], 0.f),
                         fmaxf(bf2f((unsigned short)g[3]) - ca[3], 0.f));
    u.u[2] = cvt_pk_bf16(fmaxf(bf2f((unsigned short)g[4]) - cb[0], 0.f),
                         fmaxf(bf2f((unsigned short)g[5]) - cb[1], 0.f));
    u.u[3] = cvt_pk_bf16(fmaxf(bf2f((unsigned short)g[6]) - cb[2], 0.f),
                         fmaxf(bf2f((unsigned short)g[7]) - cb[3], 0.f));
    return u.s8;
}

// ---------------------------------------------------------------------------
// Weight packing (round-13 version, verified).
// ---------------------------------------------------------------------------
__global__ void pack_weights_k(const float* __restrict__ offW1,
                               const float* __restrict__ eW1,
                               const float* __restrict__ eW2,
                               const float* __restrict__ uW1,
                               const float* __restrict__ uW2,
                               const float* __restrict__ eb1,
                               unsigned short* __restrict__ offW1p,
                               unsigned short* __restrict__ eW1fp,
                               unsigned short* __restrict__ eW2p,
                               unsigned short* __restrict__ uW1p,
                               unsigned short* __restrict__ uW2p,
                               float* __restrict__ eW1rTp)
{
    int i = blockIdx.x * 256 + threadIdx.x;
    if (i < 16384) { offW1p[i] = f2bf(offW1[i]); return; }
    i -= 16384;
    if (i < 49152) {
        int tt = i / 16384, rem = i % 16384;
        int o = rem / 128, k = rem % 128;
        eW1fp[i] = f2bf(eW1[(tt * 128 + o) * 131 + 3 + k]);
        return;
    }
    i -= 49152;
    if (i < 49152) { eW2p[i] = f2bf(eW2[i]); return; }
    i -= 49152;
    if (i < 98304) { uW1p[i] = f2bf(uW1[i]); return; }
    i -= 98304;
    if (i < 49152) { uW2p[i] = f2bf(uW2[i]); return; }
    i -= 49152;
    if (i < 1536) {
        int tt = i / 512, rem = i % 512;
        int j = rem / 128, col = rem % 128;
        eW1rTp[i] = (j < 3) ? eW1[(size_t)(tt * 128 + col) * 131 + j]
                            : eb1[tt * 128 + col];
    }
}

// ---------------------------------------------------------------------------
// center_k: round-13 version (verified).
// ---------------------------------------------------------------------------
__global__ __launch_bounds__(256, 4)
void center_k(const float* __restrict__ Fin, const float* __restrict__ xyz,
              const unsigned short* __restrict__ offW1p,
              const float* __restrict__ offW2, const float* __restrict__ offb1,
              const float* __restrict__ offb2,
              const unsigned short* __restrict__ eW1fp,
              const float* __restrict__ eW1rT0,   // packed [4][128] (t=0)
              unsigned short* __restrict__ Gbf, float* __restrict__ ctr)
{
    __shared__ __align__(16) unsigned short sA[32 * HW_];
    __shared__ __align__(16) unsigned short sH[32 * HW_];
    __shared__ float s_XY[96];
    const int t = threadIdx.x, wv = t >> 6, ln = t & 63, q = ln >> 4, r = ln & 15;
    const int cg0 = wv << 1;
    const int base = blockIdx.x * 32;

    {   // 32x128 fp32 -> bf16 -> sA
        int row = t >> 3, c16 = (t & 7) * 16;
        const float* src = Fin + (size_t)(base + row) * NC + c16;
        float4 f0 = *(const float4*)src;
        float4 f1 = *(const float4*)(src + 4);
        float4 f2 = *(const float4*)(src + 8);
        float4 f3 = *(const float4*)(src + 12);
        short8 u0, u1;
        u0[0]=f2bf(f0.x); u0[1]=f2bf(f0.y); u0[2]=f2bf(f0.z); u0[3]=f2bf(f0.w);
        u0[4]=f2bf(f1.x); u0[5]=f2bf(f1.y); u0[6]=f2bf(f1.z); u0[7]=f2bf(f1.w);
        u1[0]=f2bf(f2.x); u1[1]=f2bf(f2.y); u1[2]=f2bf(f2.z); u1[3]=f2bf(f2.w);
        u1[4]=f2bf(f3.x); u1[5]=f2bf(f3.y); u1[6]=f2bf(f3.z); u1[7]=f2bf(f3.w);
        *(short8*)&sA[row * HW_ + c16]     = u0;
        *(short8*)&sA[row * HW_ + c16 + 8] = u1;
    }
    if (t < 96) s_XY[t] = xyz[(size_t)base * 3 + t];
    __syncthreads();

    floatx4 agk[2][2];
    {   // offset L1 + G-GEMM
        short8 wo[2][4], wg[2][4];
#pragma unroll
        for (int c = 0; c < 2; ++c)
#pragma unroll
            for (int ks = 0; ks < 4; ++ks) {
                wo[c][ks] = *(const short8*)(offW1p + ((cg0 + c) * 16 + r) * NC + ks * 32 + q * 8);
                wg[c][ks] = *(const short8*)(eW1fp  + ((cg0 + c) * 16 + r) * NC + ks * 32 + q * 8);
            }
        float bo[2] = { offb1[cg0 * 16 + r], offb1[(cg0 + 1) * 16 + r] };
#pragma unroll
        for (int rt = 0; rt < 2; ++rt) {
            short8 af[4];
#pragma unroll
            for (int ks = 0; ks < 4; ++ks)
                af[ks] = *(const short8*)&sA[(rt * 16 + r) * HW_ + ks * 32 + q * 8];
            floatx4 ao[2] = { {0.f,0.f,0.f,0.f}, {0.f,0.f,0.f,0.f} };
            floatx4 ag[2] = { {0.f,0.f,0.f,0.f}, {0.f,0.f,0.f,0.f} };
#pragma unroll
            for (int c = 0; c < 2; ++c)
#pragma unroll
                for (int ks = 0; ks < 4; ++ks) {
                    ao[c] = MFMA(af[ks], wo[c][ks], ao[c]);
                    ag[c] = MFMA(af[ks], wg[c][ks], ag[c]);
                }
#pragma unroll
            for (int c = 0; c < 2; ++c) {
                int col = (cg0 + c) * 16 + r;
#pragma unroll
                for (int i = 0; i < 4; ++i)
                    sH[(rt * 16 + q * 4 + i) * HW_ + col] = f2bf(fmaxf(ao[c][i] + bo[c], 0.f));
                agk[rt][c] = ag[c];
            }
        }
    }
    __syncthreads();

    {   // stage G~ -> sA with xyz*W1r + b1 fold (packed, coalesced)
#pragma unroll
        for (int c = 0; c < 2; ++c) {
            int col = (cg0 + c) * 16 + r;
            float w0 = eW1rT0[col], w1 = eW1rT0[128 + col];
            float w2 = eW1rT0[256 + col], b1v = eW1rT0[384 + col];
#pragma unroll
            for (int rt = 0; rt < 2; ++rt)
#pragma unroll
                for (int i = 0; i < 4; ++i) {
                    int row = rt * 16 + q * 4 + i;
                    sA[row * HW_ + col] = f2bf(agk[rt][c][i]
                        + s_XY[row * 3 + 0] * w0 + s_XY[row * 3 + 1] * w1
                        + s_XY[row * 3 + 2] * w2 + b1v);
                }
        }
    }
    if (wv < 2) {   // offset L2 (out=3)
        int rt = wv;
        short8 wf[4];
#pragma unroll
        for (int ks = 0; ks < 4; ++ks) {
            short8 u = {0,0,0,0,0,0,0,0};
            if (r < 3) {
                const float* w = offW2 + r * NC + ks * 32 + q * 8;
                float4 f0 = *(const float4*)w;
                float4 f1 = *(const float4*)(w + 4);
                u[0]=f2bf(f0.x); u[1]=f2bf(f0.y); u[2]=f2bf(f0.z); u[3]=f2bf(f0.w);
                u[4]=f2bf(f1.x); u[5]=f2bf(f1.y); u[6]=f2bf(f1.z); u[7]=f2bf(f1.w);
            }
            wf[ks] = u;
        }
        short8 af[4];
#pragma unroll
        for (int ks = 0; ks < 4; ++ks)
            af[ks] = *(const short8*)&sH[(rt * 16 + r) * HW_ + ks * 32 + q * 8];
        floatx4 acc = {0.f, 0.f, 0.f, 0.f};
#pragma unroll
        for (int ks = 0; ks < 4; ++ks)
            acc = MFMA(af[ks], wf[ks], acc);
        if (r < 3) {
#pragma unroll
            for (int i = 0; i < 4; ++i) {
                int p = rt * 16 + q * 4 + i;
                ctr[(size_t)(base + p) * 3 + r] =
                    xyz[(size_t)(base + p) * 3 + r] + acc[i] + offb2[r];
            }
        }
    }
    __syncthreads();

    {   // coalesced Gbf write
        int row = t >> 3, c16 = (t & 7) * 16;
        *(short8*)(Gbf + (size_t)(base + row) * NC + c16)     = *(short8*)&sA[row * HW_ + c16];
        *(short8*)(Gbf + (size_t)(base + row) * NC + c16 + 8) = *(short8*)&sA[row * HW_ + c16 + 8];
    }
}

// ---------------------------------------------------------------------------
// edge_k v8 = round-13 v6 with ONE change: __launch_bounds__(256, 3).
// Cross-round occupancy data: (256,2) kernels run 25-27% occupancy;
// (256,3)/(256,4) kernels run 37-40%. Mechanism: waves/CU halves at
// combined VGPR+AGPR = {64,128,256}; at (256,2) the allocator spends into
// the 129-256 bucket (68 arch + AGPR granularity ≈ 132) -> 8 waves/CU cap.
// (256,3) forces combined <= ~170 -> 12 waves/CU -> 1.5x latency-hiding.
// Persistent state (kn 8 + g0/g1 32 + wf2 16 = 56) fits the ~84 arch cap.
// ---------------------------------------------------------------------------
__global__ __launch_bounds__(256, 3)
void edge_k(const unsigned short* __restrict__ Gbf,
            const int* __restrict__ knn,
            const float* __restrict__ ctr,
            const float* __restrict__ eW1rT,   // packed [4][128] + t*512
            const float* __restrict__ eb2,
            const unsigned short* __restrict__ eW2p,
            unsigned short* __restrict__ aggG)
{
    __shared__ __align__(16) unsigned short s_H[64 * GIW];    // 17408 B
    __shared__ __align__(16) float s_C[8 * CW];               // 4224 B
    __shared__ __align__(16) unsigned short s_AGB[8 * AGW];   // 2176 B

    // XCD swizzle: batch b -> XCDs {2b, 2b+1}
    const int xcd  = blockIdx.x & 7;
    const int slot = blockIdx.x >> 3;
    const int b    = xcd >> 1;
    const int n0   = ((slot << 1) | (xcd & 1)) << 3;
    const int t = threadIdx.x, wv = t >> 6, ln = t & 63;
    const int q = ln >> 4, r = ln & 15, cg0 = wv << 1;
    const int base = b * NP + n0;
    const int rr = t >> 4, c8 = (t & 15) * 8;

    // ---- P0: knn, BOTH gather halves, W2 frags, C-table (packed W1rT)
    const int* kb = knn + (size_t)base * NK;
    int kn[8];
#pragma unroll
    for (int j = 0; j < 8; ++j) kn[j] = kb[j * 16 + rr];
    short8 g0[4], g1[4];
#pragma unroll
    for (int p = 0; p < 4; ++p)
        g0[p] = *(const short8*)(Gbf + (size_t)(b * NP + kn[p]) * NC + c8);
#pragma unroll
    for (int p = 0; p < 4; ++p)
        g1[p] = *(const short8*)(Gbf + (size_t)(b * NP + kn[4 + p]) * NC + c8);

    short8 wf2[2][4];
#pragma unroll
    for (int c = 0; c < 2; ++c)
#pragma unroll
        for (int ks = 0; ks < 4; ++ks)
            wf2[c][ks] = *(const short8*)(eW2p + ((cg0 + c) * 16 + r) * NC + ks * 32 + q * 8);
    float eb2v[2] = { eb2[cg0 * 16 + r], eb2[(cg0 + 1) * 16 + r] };

    {   // C[p][col] = ctr[p] . W1r[col] — coalesced packed rows
        int p = t >> 5, c0 = (t & 31) * 4;
        float cx = ctr[(size_t)(base + p) * 3 + 0];
        float cy = ctr[(size_t)(base + p) * 3 + 1];
        float cz = ctr[(size_t)(base + p) * 3 + 2];
        floatx4 w0 = *(const floatx4*)(eW1rT + c0);
        floatx4 w1 = *(const floatx4*)(eW1rT + 128 + c0);
        floatx4 w2 = *(const floatx4*)(eW1rT + 256 + c0);
#pragma unroll
        for (int k = 0; k < 4; ++k)
            s_C[p * CW + c0 + k] = cx * w0[k] + cy * w1[k] + cz * w2[k];
    }
    __syncthreads();   // ==== A: C ready ====

    // ---- xform half-0 -> s_H
#pragma unroll
    for (int p = 0; p < 4; ++p) {
        const float* cp = &s_C[p * CW + c8];
        floatx4 ca = *(const floatx4*)(cp);
        floatx4 cb = *(const floatx4*)(cp + 4);
        *(short8*)&s_H[(p * 16 + rr) * GIW + c8] = xform(g0[p], ca, cb);
    }
    __syncthreads();   // ==== B: H half-0 ready ====

    // ---- MFMA half-0 + maxK
#pragma unroll
    for (int rt = 0; rt < 4; ++rt) {
        short8 af[4];
#pragma unroll
        for (int ks = 0; ks < 4; ++ks)
            af[ks] = *(const short8*)&s_H[(rt * 16 + r) * GIW + ks * 32 + q * 8];
        floatx4 acc[2] = { {0.f,0.f,0.f,0.f}, {0.f,0.f,0.f,0.f} };
#pragma unroll
        for (int c = 0; c < 2; ++c)
#pragma unroll
            for (int ks = 0; ks < 4; ++ks)
                acc[c] = MFMA(af[ks], wf2[c][ks], acc[c]);
#pragma unroll
        for (int c = 0; c < 2; ++c) {
            float m = fmaxf(fmaxf(acc[c][0], acc[c][1]), fmaxf(acc[c][2], acc[c][3]));
            m = fmaxf(m, __shfl_xor(m, 16));
            m = fmaxf(m, __shfl_xor(m, 32));
            if (q == 0)
                s_AGB[rt * AGW + (cg0 + c) * 16 + r] = f2bf(m + eb2v[c]);
        }
    }
    __syncthreads();   // ==== C: H half-0 consumed ====

    // ---- xform half-1 -> s_H
#pragma unroll
    for (int p = 0; p < 4; ++p) {
        const float* cp = &s_C[(4 + p) * CW + c8];
        floatx4 ca = *(const floatx4*)(cp);
        floatx4 cb = *(const floatx4*)(cp + 4);
        *(short8*)&s_H[(p * 16 + rr) * GIW + c8] = xform(g1[p], ca, cb);
    }
    __syncthreads();   // ==== D: H half-1 ready ====

    // ---- MFMA half-1 + maxK
#pragma unroll
    for (int rt = 0; rt < 4; ++rt) {
        short8 af[4];
#pragma unroll
        for (int ks = 0; ks < 4; ++ks)
            af[ks] = *(const short8*)&s_H[(rt * 16 + r) * GIW + ks * 32 + q * 8];
        floatx4 acc[2] = { {0.f,0.f,0.f,0.f}, {0.f,0.f,0.f,0.f} };
#pragma unroll
        for (int c = 0; c < 2; ++c)
#pragma unroll
            for (int ks = 0; ks < 4; ++ks)
                acc[c] = MFMA(af[ks], wf2[c][ks], acc[c]);
#pragma unroll
        for (int c = 0; c < 2; ++c) {
            float m = fmaxf(fmaxf(acc[c][0], acc[c][1]), fmaxf(acc[c][2], acc[c][3]));
            m = fmaxf(m, __shfl_xor(m, 16));
            m = fmaxf(m, __shfl_xor(m, 32));
            if (q == 0)
                s_AGB[(4 + rt) * AGW + (cg0 + c) * 16 + r] = f2bf(m + eb2v[c]);
        }
    }
    __syncthreads();   // ==== E: AGG ready ====

    if (t < 128) {
        int row = t >> 4, cc = (t & 15) * 8;
        *(short8*)(aggG + (size_t)(base + row) * NC + cc) = *(short8*)&s_AGB[row * AGW + cc];
    }
}

// ---------------------------------------------------------------------------
// upd_k: round-13 version (verified).
// ---------------------------------------------------------------------------
__global__ __launch_bounds__(256, 3)
void upd_k(const float* __restrict__ Fin, float* __restrict__ Fout,
           const unsigned short* __restrict__ aggG,
           const float* __restrict__ xyz,
           const unsigned short* __restrict__ uW1p,
           const unsigned short* __restrict__ uW2p,
           const float* __restrict__ ub1, const float* __restrict__ ub2,
           const unsigned short* __restrict__ eW1fpN,   // next iter G-proj (bf16)
           const float* __restrict__ eW1rTN,            // next iter packed [4][128]
           const unsigned short* __restrict__ offW1p,
           const float* __restrict__ offW2, const float* __restrict__ offb1,
           const float* __restrict__ offb2,
           unsigned short* __restrict__ Gbf, float* __restrict__ ctrOut,
           int doNext)
{
    __shared__ __align__(16) unsigned short s_UIN[32 * UINW];  // 16896 B
    __shared__ __align__(16) unsigned short s_H[32 * HUW];     // 8704 B
    __shared__ __align__(16) unsigned short s_FN[32 * HUW];    // 8704 B
    __shared__ float s_XY[96];

    const int xcd  = blockIdx.x & 7;
    const int slot = blockIdx.x >> 3;
    const int b    = xcd >> 1;
    const int n0   = ((slot << 1) | (xcd & 1)) << 5;   // *32
    const int t = threadIdx.x, wv = t >> 6, ln = t & 63;
    const int q = ln >> 4, r = ln & 15, cg0 = wv << 1;
    const int base = b * NP + n0;
    const int row32 = t >> 3, c16 = (t & 7) * 16;

    // ---- P0: stage UIN = [agg(bf16) | self(f32->bf16)] for 32 rows; xyz
    {
        const unsigned short* ap = aggG + (size_t)(base + row32) * NC + c16;
        *(short8*)&s_UIN[row32 * UINW + c16]     = *(const short8*)ap;
        *(short8*)&s_UIN[row32 * UINW + c16 + 8] = *(const short8*)(ap + 8);
        const float* src = Fin + (size_t)(base + row32) * NC + c16;
        float4 f0 = *(const float4*)src;
        float4 f1 = *(const float4*)(src + 4);
        float4 f2 = *(const float4*)(src + 8);
        float4 f3 = *(const float4*)(src + 12);
        short8 u0, u1;
        u0[0]=f2bf(f0.x); u0[1]=f2bf(f0.y); u0[2]=f2bf(f0.z); u0[3]=f2bf(f0.w);
        u0[4]=f2bf(f1.x); u0[5]=f2bf(f1.y); u0[6]=f2bf(f1.z); u0[7]=f2bf(f1.w);
        u1[0]=f2bf(f2.x); u1[1]=f2bf(f2.y); u1[2]=f2bf(f2.z); u1[3]=f2bf(f2.w);
        u1[4]=f2bf(f3.x); u1[5]=f2bf(f3.y); u1[6]=f2bf(f3.z); u1[7]=f2bf(f3.w);
        *(short8*)&s_UIN[row32 * UINW + 128 + c16]     = u0;
        *(short8*)&s_UIN[row32 * UINW + 128 + c16 + 8] = u1;
    }
    if (t < 96) s_XY[t] = xyz[(size_t)base * 3 + t];
    __syncthreads();   // ==== A ====

    // ---- upd-L1 (K=256) -> H, 2 row-tiles per weight load
    {
        short8 wfa[2][8];
#pragma unroll
        for (int c = 0; c < 2; ++c)
#pragma unroll
            for (int ks = 0; ks < 8; ++ks)
                wfa[c][ks] = *(const short8*)(uW1p + ((cg0 + c) * 16 + r) * 256 + ks * 32 + q * 8);
        float ub1v[2] = { ub1[cg0 * 16 + r], ub1[(cg0 + 1) * 16 + r] };
#pragma unroll
        for (int rt = 0; rt < 2; ++rt) {
            short8 af[8];
#pragma unroll
            for (int ks = 0; ks < 8; ++ks)
                af[ks] = *(const short8*)&s_UIN[(rt * 16 + r) * UINW + ks * 32 + q * 8];
            floatx4 acc3[2] = { {0.f,0.f,0.f,0.f}, {0.f,0.f,0.f,0.f} };
#pragma unroll
            for (int c = 0; c < 2; ++c)
#pragma unroll
                for (int ks = 0; ks < 8; ++ks)
                    acc3[c] = MFMA(af[ks], wfa[c][ks], acc3[c]);
#pragma unroll
            for (int c = 0; c < 2; ++c)
#pragma unroll
                for (int i = 0; i < 4; ++i)
                    s_H[(rt * 16 + q * 4 + i) * HUW + (cg0 + c) * 16 + r] =
                        f2bf(fmaxf(acc3[c][i] + ub1v[c], 0.f));
        }
    }
    __syncthreads();   // ==== B ====

    // ---- upd-L2 + residual -> Fout; Fnew bf16 -> s_FN
    {
        short8 wfb[2][4];
#pragma unroll
        for (int c = 0; c < 2; ++c)
#pragma unroll
            for (int ks = 0; ks < 4; ++ks)
                wfb[c][ks] = *(const short8*)(uW2p + ((cg0 + c) * 16 + r) * NC + ks * 32 + q * 8);
        float ub2v[2] = { ub2[cg0 * 16 + r], ub2[(cg0 + 1) * 16 + r] };
#pragma unroll
        for (int rt = 0; rt < 2; ++rt) {
            short8 af[4];
#pragma unroll
            for (int ks = 0; ks < 4; ++ks)
                af[ks] = *(const short8*)&s_H[(rt * 16 + r) * HUW + ks * 32 + q * 8];
            floatx4 acc[2] = { {0.f,0.f,0.f,0.f}, {0.f,0.f,0.f,0.f} };
#pragma unroll
            for (int c = 0; c < 2; ++c)
#pragma unroll
                for (int ks = 0; ks < 4; ++ks)
                    acc[c] = MFMA(af[ks], wfb[c][ks], acc[c]);
#pragma unroll
            for (int c = 0; c < 2; ++c) {
                int col = (cg0 + c) * 16 + r;
#pragma unroll
                for (int i = 0; i < 4; ++i) {
                    int p = rt * 16 + q * 4 + i;   // 0..31
                    float fnew = Fin[(size_t)(base + p) * NC + col] + acc[c][i] + ub2v[c];
                    Fout[(size_t)(base + p) * NC + col] = fnew;
                    s_FN[p * HUW + col] = f2bf(fnew);
                }
            }
        }
    }

    if (doNext) {
        __syncthreads();   // ==== C ====
        // ---- G~' = Fnew*W1f^T + xyz*W1rN + b1N -> s_UIN; off-L1 -> s_H
        {
            short8 wg[2][4], wo[2][4];
#pragma unroll
            for (int c = 0; c < 2; ++c)
#pragma unroll
                for (int ks = 0; ks < 4; ++ks) {
                    wg[c][ks] = *(const short8*)(eW1fpN + ((cg0 + c) * 16 + r) * NC + ks * 32 + q * 8);
                    wo[c][ks] = *(const short8*)(offW1p + ((cg0 + c) * 16 + r) * NC + ks * 32 + q * 8);
                }
            float bo[2] = { offb1[cg0 * 16 + r], offb1[(cg0 + 1) * 16 + r] };
#pragma unroll
            for (int rt = 0; rt < 2; ++rt) {
                short8 af[4];
#pragma unroll
                for (int ks = 0; ks < 4; ++ks)
                    af[ks] = *(const short8*)&s_FN[(rt * 16 + r) * HUW + ks * 32 + q * 8];
                floatx4 ag[2] = { {0.f,0.f,0.f,0.f}, {0.f,0.f,0.f,0.f} };
                floatx4 ao[2] = { {0.f,0.f,0.f,0.f}, {0.f,0.f,0.f,0.f} };
#pragma unroll
                for (int c = 0; c < 2; ++c)
#pragma unroll
                    for (int ks = 0; ks < 4; ++ks) {
                        ag[c] = MFMA(af[ks], wg[c][ks], ag[c]);
                        ao[c] = MFMA(af[ks], wo[c][ks], ao[c]);
                    }
#pragma unroll
                for (int c = 0; c < 2; ++c) {
                    int col = (cg0 + c) * 16 + r;
                    float w0 = eW1rTN[col], w1 = eW1rTN[128 + col];
                    float w2 = eW1rTN[256 + col], b1v = eW1rTN[384 + col];
#pragma unroll
                    for (int i = 0; i < 4; ++i) {
                        int p = rt * 16 + q * 4 + i;
                        s_UIN[p * UINW + col] = f2bf(ag[c][i]
                            + s_XY[p * 3 + 0] * w0 + s_XY[p * 3 + 1] * w1
                            + s_XY[p * 3 + 2] * w2 + b1v);
                        s_H[p * HUW + col]    = f2bf(fmaxf(ao[c][i] + bo[c], 0.f));
                    }
                }
            }
        }
        __syncthreads();   // ==== D ====

        // coalesced Gbf dump (32 rows)
        *(short8*)(Gbf + (size_t)(base + row32) * NC + c16) =
            *(short8*)&s_UIN[row32 * UINW + c16];
        *(short8*)(Gbf + (size_t)(base + row32) * NC + c16 + 8) =
            *(short8*)&s_UIN[row32 * UINW + c16 + 8];

        if (wv < 2) {   // off-L2 (out=3) -> ctr', one 16-row tile per wave
            int rt = wv;
            short8 wf[4];
#pragma unroll
            for (int ks = 0; ks < 4; ++ks) {
                short8 u = {0,0,0,0,0,0,0,0};
                if (r < 3) {
                    const float* w = offW2 + r * NC + ks * 32 + q * 8;
                    float4 f0 = *(const float4*)w;
                    float4 f1 = *(const float4*)(w + 4);
                    u[0]=f2bf(f0.x); u[1]=f2bf(f0.y); u[2]=f2bf(f0.z); u[3]=f2bf(f0.w);
                    u[4]=f2bf(f1.x); u[5]=f2bf(f1.y); u[6]=f2bf(f1.z); u[7]=f2bf(f1.w);
                }
                wf[ks] = u;
            }
            short8 af[4];
#pragma unroll
            for (int ks = 0; ks < 4; ++ks)
                af[ks] = *(const short8*)&s_H[(rt * 16 + r) * HUW + ks * 32 + q * 8];
            floatx4 acc = {0.f, 0.f, 0.f, 0.f};
#pragma unroll
            for (int ks = 0; ks < 4; ++ks)
                acc = MFMA(af[ks], wf[ks], acc);
            if (r < 3) {
#pragma unroll
                for (int i = 0; i < 4; ++i) {
                    int p = rt * 16 + q * 4 + i;
                    ctrOut[(size_t)(base + p) * 3 + r] =
                        xyz[(size_t)(base + p) * 3 + r] + acc[i] + offb2[r];
                }
            }
        }
    }
}

// ---------------------------------------------------------------------------
extern "C" void kernel_launch(void* const* d_in, const int* in_sizes, int n_in,
                              void* d_out, int out_size, void* d_ws, size_t ws_size,
                              hipStream_t stream)
{
    const float* xyz   = (const float*)d_in[0];
    const float* feat  = (const float*)d_in[1];
    const int*   knn   = (const int*)d_in[2];
    const float* offW1 = (const float*)d_in[3];
    const float* offb1 = (const float*)d_in[4];
    const float* offW2 = (const float*)d_in[5];
    const float* offb2 = (const float*)d_in[6];
    const float* eW1   = (const float*)d_in[7];
    const float* eb1   = (const float*)d_in[8];
    const float* eW2   = (const float*)d_in[9];
    const float* eb2   = (const float*)d_in[10];
    const float* uW1   = (const float*)d_in[11];
    const float* ub1   = (const float*)d_in[12];
    const float* uW2   = (const float*)d_in[13];
    const float* ub2   = (const float*)d_in[14];
    float* out = (float*)d_out;

    char* ws = (char*)d_ws;
    unsigned short* Gbf    = (unsigned short*)ws;                 // 8388608 B
    float*          ctrb   = (float*)(ws + 8388608);              // 393216 B
    unsigned short* offW1p = (unsigned short*)(ws + 8781824);     // 32768 B
    unsigned short* eW1fp  = (unsigned short*)(ws + 8814592);     // 98304 B
    unsigned short* eW2p   = (unsigned short*)(ws + 8912896);     // 98304 B
    unsigned short* uW1p   = (unsigned short*)(ws + 9011200);     // 196608 B
    unsigned short* uW2p   = (unsigned short*)(ws + 9207808);     // 98304 B
    unsigned short* aggG   = (unsigned short*)(ws + 9306112);     // 8388608 B
    float*          eW1rTp = (float*)(ws + 17694720);             // 6144 B

    pack_weights_k<<<1030, 256, 0, stream>>>(offW1, eW1, eW2, uW1, uW2, eb1,
                                             offW1p, eW1fp, eW2p, uW1p, uW2p,
                                             eW1rTp);

    // initial G~(0), ctr(0) from feat
    center_k<<<1024, 256, 0, stream>>>(feat, xyz, offW1p, offW2,
                                       offb1, offb2, eW1fp, eW1rTp,
                                       Gbf, ctrb);

    for (int tt = 0; tt < 3; ++tt) {
        int ntt = (tt + 1) % 3;
        edge_k<<<4096, 256, 0, stream>>>(
            Gbf, knn, ctrb,
            eW1rTp + tt * 512, eb2 + tt * 128,
            eW2p + tt * 16384, aggG);
        const float* fin = (tt == 0) ? feat : out;
        upd_k<<<1024, 256, 0, stream>>>(
            fin, out, aggG, xyz,
            uW1p + tt * 32768, uW2p + tt * 16384, ub1 + tt * 128, ub2 + tt * 128,
            eW1fp + ntt * 16384, eW1rTp + ntt * 512,
            offW1p, offW2, offb1, offb2,
            Gbf, ctrb, (tt < 2) ? 1 : 0);
    }
}